// Round 8
// baseline (340.662 us; speedup 1.0000x reference)
//
#include <hip/hip_runtime.h>
#include <hip/hip_fp8.h>

// ---------------------------------------------------------------------------
// GraphSAGE 2-layer encoder, MI355X.
//   out = leaky( mean_{j->i}(h_j) @ Wl + b + h_i @ Wr ), slope 0.5, x2 layers
// R8: GEMM inner loop made load-free. Wave owns 16 cols; its B column-slice
// (16 cols x K=512 = breg[16] bf16x8 = 64 VGPR) is register-resident for the
// whole block. Block = 64 rows x 64 cols, A-tile 64KB LDS (XOR-swizzled,
// global_load_lds). k-loop = 4 ds_read + 4 MFMA only. B L2 traffic /4.
// Rest unchanged from R7 (counting-sort binA, fp8 agg, parallel scan).
// ---------------------------------------------------------------------------

typedef __attribute__((ext_vector_type(8))) short bf16x8;
typedef __attribute__((ext_vector_type(4))) float f32x4;

__device__ __forceinline__ float bf2f(unsigned short b) {
    union { unsigned u; float f; } x; x.u = ((unsigned)b) << 16; return x.f;
}
__device__ __forceinline__ short f2bf(float f) {
    union { float f; unsigned u; } x; x.f = f;
    unsigned r = x.u + 0x7fffu + ((x.u >> 16) & 1u);
    return (short)(r >> 16);
}
__device__ __forceinline__ unsigned char f2fp8(float f) {
    __hip_fp8_e4m3 q(f);
    return (unsigned char)q.__x;
}
__device__ __forceinline__ float fp82f(unsigned char b) {
    __hip_fp8_e4m3 q; q.__x = (__hip_fp8_storage_t)b;
    return (float)q;
}

// -------------------- CSR construction --------------------

__global__ __launch_bounds__(256) void zero_kernel(int* __restrict__ p, int n4) {
    int i = blockIdx.x * 256 + threadIdx.x;
    if (i < n4) *reinterpret_cast<int4*>(p + i * 4) = (int4){0, 0, 0, 0};
}

__global__ __launch_bounds__(256) void count_kernel(
    const int* __restrict__ ei, int* __restrict__ cnt, int E) {
    int e = blockIdx.x * 256 + threadIdx.x;
    if (e < E) atomicAdd(&cnt[ei[E + e]], 1);
}

// scan1: per-block (1024) local exclusive scan of cnt -> offs, block sums.
__global__ __launch_bounds__(1024) void scan1_kernel(
    const int* __restrict__ cnt, int* __restrict__ offs,
    float* __restrict__ invdeg, int* __restrict__ bsum, int N) {
    __shared__ int wsum[16];
    int lane = threadIdx.x & 63;
    int wid = threadIdx.x >> 6;
    int i = blockIdx.x * 1024 + threadIdx.x;
    int v = (i < N) ? cnt[i] : 0;
    int s = v;
    #pragma unroll
    for (int d = 1; d < 64; d <<= 1) {
        int t = __shfl_up(s, d, 64);
        if (lane >= d) s += t;
    }
    if (lane == 63) wsum[wid] = s;
    __syncthreads();
    if (wid == 0) {
        int w = (lane < 16) ? wsum[lane] : 0;
        int ws = w;
        #pragma unroll
        for (int d = 1; d < 16; d <<= 1) {
            int t = __shfl_up(ws, d, 64);
            if (lane >= d) ws += t;
        }
        if (lane < 16) wsum[lane] = ws - w;          // exclusive wave prefix
    }
    __syncthreads();
    if (i < N) {
        offs[i] = wsum[wid] + s - v;                 // block-local exclusive
        invdeg[i] = 1.0f / (float)(v > 0 ? v : 1);
    }
    if (threadIdx.x == 1023) bsum[blockIdx.x] = wsum[15] + s;
}

__global__ __launch_bounds__(64) void scan2_kernel(
    const int* __restrict__ bsum, int* __restrict__ bpre,
    int* __restrict__ offs, int NB, int N) {
    int lane = threadIdx.x;
    int v = (lane < NB) ? bsum[lane] : 0;
    int s = v;
    #pragma unroll
    for (int d = 1; d < 64; d <<= 1) {
        int t = __shfl_up(s, d, 64);
        if (lane >= d) s += t;
    }
    if (lane < NB) bpre[lane] = s - v;
    if (lane == NB - 1) offs[N] = s;
}

__global__ __launch_bounds__(1024) void scan3_kernel(
    int* __restrict__ offs, const int* __restrict__ bpre, int N) {
    int i = blockIdx.x * 1024 + threadIdx.x;
    if (i < N) offs[i] += bpre[blockIdx.x];
}

// bucket cursors: bucket b covers nodes [b*128, b*128+128); base = offs[b*128]
__global__ __launch_bounds__(256) void initcur_kernel(
    const int* __restrict__ offs, int* __restrict__ bcur, int NBK) {
    int b = blockIdx.x * 256 + threadIdx.x;
    if (b < NBK) bcur[b] = offs[b << 7];
}

// pass A (counting sort per block): chunk = 8192 edges; LDS histogram,
// one global atomic per (block,bucket), LDS cursors hold global positions.
#define BINA_CHUNK 8192
__global__ __launch_bounds__(512) void binA_kernel(
    const int* __restrict__ ei, int* __restrict__ bcur,
    long long* __restrict__ pairs, int E, int NBK) {
    __shared__ int hist[512];
    int base_e = blockIdx.x * BINA_CHUNK;
    int nloc = E - base_e;
    if (nloc > BINA_CHUNK) nloc = BINA_CHUNK;
    for (int b = threadIdx.x; b < NBK; b += 512) hist[b] = 0;
    __syncthreads();
    for (int t = threadIdx.x; t < nloc; t += 512)
        atomicAdd(&hist[ei[E + base_e + t] >> 7], 1);
    __syncthreads();
    for (int b = threadIdx.x; b < NBK; b += 512) {
        int h = hist[b];
        hist[b] = (h > 0) ? atomicAdd(&bcur[b], h) : 0;
    }
    __syncthreads();
    for (int t = threadIdx.x; t < nloc; t += 512) {
        int dst = ei[E + base_e + t];
        int src = ei[base_e + t];
        int pos = atomicAdd(&hist[dst >> 7], 1);
        pairs[pos] = ((long long)dst << 32) | (unsigned)src;
    }
}

// pass B: one block per bucket; LDS cursors; csr writes land in 8KB window.
__global__ __launch_bounds__(256) void binB_kernel(
    const long long* __restrict__ pairs, const int* __restrict__ offs,
    int* __restrict__ csr, int NBK, int N, int E) {
    __shared__ int cur[128];
    int b = blockIdx.x;
    int t = threadIdx.x;
    if (t < 128) {
        int n0 = (b << 7) + t;
        cur[t] = (n0 < N) ? offs[n0] : 0;
    }
    __syncthreads();
    int beg = offs[b << 7];
    int eidx = (b + 1) << 7;
    if (eidx > N) eidx = N;
    int end = offs[eidx];
    for (int i = beg + t; i < end; i += 256) {
        long long p = pairs[i];
        int dst = (int)(p >> 32);
        int src = (int)(p & 0xffffffffLL);
        int pos = atomicAdd(&cur[dst & 127], 1);
        csr[pos] = src;
    }
}

// -------------------- casts / weight prep --------------------

// x f32 -> xb bf16, xq fp8, and copy x into d_out second half.
__global__ __launch_bounds__(256) void cast_x_kernel(
    const float* __restrict__ x, short* __restrict__ xb,
    unsigned char* __restrict__ xq, float* __restrict__ xcopy, int total8) {
    int i = blockIdx.x * 256 + threadIdx.x;
    if (i >= total8) return;
    const float* p = x + (size_t)i * 8;
    float4 v0 = *reinterpret_cast<const float4*>(p);
    float4 v1 = *reinterpret_cast<const float4*>(p + 4);
    bf16x8 t;
    t[0] = f2bf(v0.x); t[1] = f2bf(v0.y); t[2] = f2bf(v0.z); t[3] = f2bf(v0.w);
    t[4] = f2bf(v1.x); t[5] = f2bf(v1.y); t[6] = f2bf(v1.z); t[7] = f2bf(v1.w);
    *reinterpret_cast<bf16x8*>(xb + (size_t)i * 8) = t;
    uchar4 q0, q1;
    q0.x = f2fp8(v0.x); q0.y = f2fp8(v0.y); q0.z = f2fp8(v0.z); q0.w = f2fp8(v0.w);
    q1.x = f2fp8(v1.x); q1.y = f2fp8(v1.y); q1.z = f2fp8(v1.z); q1.w = f2fp8(v1.w);
    *reinterpret_cast<uchar4*>(xq + (size_t)i * 8) = q0;
    *reinterpret_cast<uchar4*>(xq + (size_t)i * 8 + 4) = q1;
    *reinterpret_cast<float4*>(xcopy + (size_t)i * 8) = v0;
    *reinterpret_cast<float4*>(xcopy + (size_t)i * 8 + 4) = v1;
}

// B^T[n][k] = (k<256 ? Wl[k][n] : Wr[k-256][n]), bf16, both layers at once.
__global__ __launch_bounds__(256) void buildB_kernel(
    const float* __restrict__ Wl0, const float* __restrict__ Wr0,
    const float* __restrict__ Wl1, const float* __restrict__ Wr1,
    short* __restrict__ B1T, short* __restrict__ B2T) {
    int idx = blockIdx.x * 256 + threadIdx.x;   // 0 .. 262143
    int sel = idx >> 17;
    int j = idx & 131071;
    int n = j >> 9;
    int k = j & 511;
    const float* Wl = sel ? Wl1 : Wl0;
    const float* Wr = sel ? Wr1 : Wr0;
    float v = (k < 256) ? Wl[k * 256 + n] : Wr[(k - 256) * 256 + n];
    (sel ? B2T : B1T)[j] = f2bf(v);
}

// -------------------- mean aggregation (fp8 gather) --------------------
// One wave per node; lane t owns elements [4t,4t+4). 8 rows in flight.
__global__ __launch_bounds__(256) void agg_kernel(
    const unsigned char* __restrict__ feat,
    const int* __restrict__ offs, const int* __restrict__ csr,
    const float* __restrict__ invdeg,
    short* __restrict__ outp, int N) {
    int wave = threadIdx.x >> 6;
    int lane = threadIdx.x & 63;
    int node = blockIdx.x * 4 + wave;
    if (node >= N) return;
    int beg = offs[node];
    int end = offs[node + 1];
    int c = lane * 4;

    float a[4][4];
    #pragma unroll
    for (int u = 0; u < 4; ++u)
        #pragma unroll
        for (int k = 0; k < 4; ++k) a[u][k] = 0.f;

    int deg = end - beg;
    int n8 = deg & ~7;
    for (int t = 0; t < n8; t += 8) {
        int s0 = csr[beg + t];     int s1 = csr[beg + t + 1];
        int s2 = csr[beg + t + 2]; int s3 = csr[beg + t + 3];
        int s4 = csr[beg + t + 4]; int s5 = csr[beg + t + 5];
        int s6 = csr[beg + t + 6]; int s7 = csr[beg + t + 7];
        unsigned u0 = *reinterpret_cast<const unsigned*>(feat + (size_t)s0 * 256 + c);
        unsigned u1 = *reinterpret_cast<const unsigned*>(feat + (size_t)s1 * 256 + c);
        unsigned u2 = *reinterpret_cast<const unsigned*>(feat + (size_t)s2 * 256 + c);
        unsigned u3 = *reinterpret_cast<const unsigned*>(feat + (size_t)s3 * 256 + c);
        unsigned u4 = *reinterpret_cast<const unsigned*>(feat + (size_t)s4 * 256 + c);
        unsigned u5 = *reinterpret_cast<const unsigned*>(feat + (size_t)s5 * 256 + c);
        unsigned u6 = *reinterpret_cast<const unsigned*>(feat + (size_t)s6 * 256 + c);
        unsigned u7 = *reinterpret_cast<const unsigned*>(feat + (size_t)s7 * 256 + c);
        #pragma unroll
        for (int k = 0; k < 4; ++k) a[0][k] += fp82f((u0 >> (8 * k)) & 0xff);
        #pragma unroll
        for (int k = 0; k < 4; ++k) a[1][k] += fp82f((u1 >> (8 * k)) & 0xff);
        #pragma unroll
        for (int k = 0; k < 4; ++k) a[2][k] += fp82f((u2 >> (8 * k)) & 0xff);
        #pragma unroll
        for (int k = 0; k < 4; ++k) a[3][k] += fp82f((u3 >> (8 * k)) & 0xff);
        #pragma unroll
        for (int k = 0; k < 4; ++k) a[0][k] += fp82f((u4 >> (8 * k)) & 0xff);
        #pragma unroll
        for (int k = 0; k < 4; ++k) a[1][k] += fp82f((u5 >> (8 * k)) & 0xff);
        #pragma unroll
        for (int k = 0; k < 4; ++k) a[2][k] += fp82f((u6 >> (8 * k)) & 0xff);
        #pragma unroll
        for (int k = 0; k < 4; ++k) a[3][k] += fp82f((u7 >> (8 * k)) & 0xff);
    }
    for (int e = beg + n8; e < end; ++e) {
        int s = csr[e];
        unsigned u = *reinterpret_cast<const unsigned*>(feat + (size_t)s * 256 + c);
        #pragma unroll
        for (int k = 0; k < 4; ++k) a[0][k] += fp82f((u >> (8 * k)) & 0xff);
    }
    float inv = invdeg[node];
    short4 o;
    o.x = f2bf((a[0][0] + a[1][0] + a[2][0] + a[3][0]) * inv);
    o.y = f2bf((a[0][1] + a[1][1] + a[2][1] + a[3][1]) * inv);
    o.z = f2bf((a[0][2] + a[1][2] + a[2][2] + a[3][2]) * inv);
    o.w = f2bf((a[0][3] + a[1][3] + a[2][3] + a[3][3]) * inv);
    *reinterpret_cast<short4*>(&outp[(size_t)node * 256 + c]) = o;
}

// -------------------- fused GEMM + bias + leaky --------------------
// C[M][256] = leaky( [AL | AR][M][512](bf16) @ B[512][256] + bias )
// Block: 64 rows x 64 cols, 4 waves; wave w owns 16 cols
//   c0 = blockIdx.y*64 + w*16.
// B column-slice register-resident: breg[16] (bf16x8 each) covers K=512 for
// the wave's 16 cols -- loaded ONCE per block, so the k-loop does only
// 4 ds_read_b128 + 4 MFMA (no global loads, no latency exposure).
// A-tile [64][512] bf16 = 64KB LDS via global_load_lds(16B), XOR-swizzled
// with (r&15) (pre-swizzled GLOBAL source, linear LDS dest).
// C/D: lane l, reg r -> row (l>>4)*4+r, col l&15.
template <int OUT_MODE>   // 0: bf16 + fp8 out, 1: f32 out
__global__ __launch_bounds__(256) void gemm_kernel(
    const short* __restrict__ AL, const short* __restrict__ AR,
    const short* __restrict__ BT, const float* __restrict__ bias,
    void* __restrict__ Cout, unsigned char* __restrict__ Cq, int M) {
    __shared__ short ldsA[64 * 512];
    int wave = threadIdx.x >> 6;
    int lane = threadIdx.x & 63;
    int row0 = blockIdx.x * 64;
    int c0 = blockIdx.y * 64 + wave * 16;
    int l16 = lane & 15;
    int lhi = lane >> 4;

    // ---- issue A-tile staging (64 rows; wave w stages rows i*4+w) ----
    #pragma unroll
    for (int i = 0; i < 16; ++i) {
        int r = i * 4 + wave;
        int grow = row0 + r;
        if (grow >= M) grow = M - 1;
        int csw = (lane * 8) ^ ((r & 15) << 3);     // swizzled short offset
        const short* src = (csw < 256) ? AL + (size_t)grow * 256 + csw
                                       : AR + (size_t)grow * 256 + (csw - 256);
        __builtin_amdgcn_global_load_lds(
            (const __attribute__((address_space(1))) unsigned int*)src,
            (__attribute__((address_space(3))) unsigned int*)&ldsA[r * 512],
            16, 0, 0);
    }

    // ---- B column-slice into registers (overlaps with staging) ----
    bf16x8 breg[16];
    #pragma unroll
    for (int kk = 0; kk < 16; ++kk)
        breg[kk] = *reinterpret_cast<const bf16x8*>(
            &BT[(size_t)(c0 + l16) * 512 + kk * 32 + lhi * 8]);

    __syncthreads();

    f32x4 acc[4];
    #pragma unroll
    for (int mt = 0; mt < 4; ++mt) acc[mt] = (f32x4){0.f, 0.f, 0.f, 0.f};

    #pragma unroll
    for (int kk = 0; kk < 16; ++kk) {
        bf16x8 a[4];
        #pragma unroll
        for (int mt = 0; mt < 4; ++mt) {
            int r = mt * 16 + l16;
            int ks = (kk * 32 + lhi * 8) ^ ((r & 15) << 3);
            a[mt] = *reinterpret_cast<const bf16x8*>(&ldsA[r * 512 + ks]);
        }
        #pragma unroll
        for (int mt = 0; mt < 4; ++mt)
            acc[mt] = __builtin_amdgcn_mfma_f32_16x16x32_bf16(
                a[mt], breg[kk], acc[mt], 0, 0, 0);
    }

    float bc = bias[c0 + l16];

    #pragma unroll
    for (int mt = 0; mt < 4; ++mt) {
        #pragma unroll
        for (int r = 0; r < 4; ++r) {
            int grow = row0 + mt * 16 + lhi * 4 + r;
            if (grow >= M) continue;
            int gcol = c0 + l16;
            float v = acc[mt][r] + bc;
            v = (v >= 0.f) ? v : 0.5f * v;
            if (OUT_MODE == 0) {
                ((short*)Cout)[(size_t)grow * 256 + gcol] = f2bf(v);
                Cq[(size_t)grow * 256 + gcol] = f2fp8(v);
            } else {
                ((float*)Cout)[(size_t)grow * 256 + gcol] = v;
            }
        }
    }
}

// -------------------- launch --------------------

extern "C" void kernel_launch(void* const* d_in, const int* in_sizes, int n_in,
                              void* d_out, int out_size, void* d_ws, size_t ws_size,
                              hipStream_t stream) {
    const float* x   = (const float*)d_in[0];
    const int*   ei  = (const int*)d_in[1];   // int64 in ref -> int32 from harness
    const float* Wl0 = (const float*)d_in[2];
    const float* bl0 = (const float*)d_in[3];
    const float* Wr0 = (const float*)d_in[4];
    const float* Wl1 = (const float*)d_in[5];
    const float* bl1 = (const float*)d_in[6];
    const float* Wr1 = (const float*)d_in[7];

    const int N = in_sizes[0] / 256;
    const int E = in_sizes[1] / 2;
    const int NBK = (N + 127) / 128;           // <= 512

    char* ws = (char*)d_ws;
    size_t o = 0;
    auto alloc = [&](size_t bytes) {
        size_t p = o;
        o = (o + bytes + 255) & ~(size_t)255;
        return p;
    };
    int*   cnt    = (int*)  (ws + alloc((size_t)N * 4));
    int*   offs   = (int*)  (ws + alloc((size_t)(N + 1) * 4));
    float* invdeg = (float*)(ws + alloc((size_t)N * 4));
    int*   bsum   = (int*)  (ws + alloc(64 * 4));
    int*   bpre   = (int*)  (ws + alloc(64 * 4));
    int*   bcur   = (int*)  (ws + alloc((size_t)NBK * 4));
    long long* pairs = (long long*)(ws + alloc((size_t)E * 8));
    int*   csr    = (int*)  (ws + alloc((size_t)E * 4));
    short* xb     = (short*)(ws + alloc((size_t)N * 256 * 2));
    short* meanb  = (short*)(ws + alloc((size_t)N * 256 * 2));   // reused L0/L1
    short* h0     = (short*)(ws + alloc((size_t)N * 256 * 2));
    unsigned char* xq  = (unsigned char*)(ws + alloc((size_t)N * 256));
    unsigned char* h0q = (unsigned char*)(ws + alloc((size_t)N * 256));
    short* B1T    = (short*)(ws + alloc(262144));
    short* B2T    = (short*)(ws + alloc(262144));

    int eb = (E + 255) / 256;
    int NB = (N + 1023) / 1024;
    zero_kernel<<<((N + 3) / 4 + 255) / 256, 256, 0, stream>>>(cnt, (N + 3) / 4);
    count_kernel<<<eb, 256, 0, stream>>>(ei, cnt, E);
    scan1_kernel<<<NB, 1024, 0, stream>>>(cnt, offs, invdeg, bsum, N);
    scan2_kernel<<<1, 64, 0, stream>>>(bsum, bpre, offs, NB, N);
    scan3_kernel<<<NB, 1024, 0, stream>>>(offs, bpre, N);
    initcur_kernel<<<(NBK + 255) / 256, 256, 0, stream>>>(offs, bcur, NBK);
    binA_kernel<<<(E + BINA_CHUNK - 1) / BINA_CHUNK, 512, 0, stream>>>(
        ei, bcur, pairs, E, NBK);
    binB_kernel<<<NBK, 256, 0, stream>>>(pairs, offs, csr, NBK, N, E);

    cast_x_kernel<<<(N * 32 + 255) / 256, 256, 0, stream>>>(
        x, xb, xq, (float*)d_out + (size_t)N * 256, N * 32);
    buildB_kernel<<<1024, 256, 0, stream>>>(Wl0, Wr0, Wl1, Wr1, B1T, B2T);

    int ab = (N + 3) / 4;
    dim3 gg((N + 63) / 64, 4);
    // layer 0
    agg_kernel<<<ab, 256, 0, stream>>>(xq, offs, csr, invdeg, meanb, N);
    gemm_kernel<0><<<gg, 256, 0, stream>>>(meanb, xb, B1T, bl0, h0, h0q, N);
    // layer 1
    agg_kernel<<<ab, 256, 0, stream>>>(h0q, offs, csr, invdeg, meanb, N);
    gemm_kernel<1><<<gg, 256, 0, stream>>>(meanb, h0, B2T, bl1, d_out, nullptr, N);
}

// Round 9
// 314.853 us; speedup vs baseline: 1.0820x; 1.0820x over previous
//
#include <hip/hip_runtime.h>
#include <hip/hip_fp8.h>

// ---------------------------------------------------------------------------
// GraphSAGE 2-layer encoder, MI355X.
//   out = leaky( mean_{j->i}(h_j) @ Wl + b + h_i @ Wr ), slope 0.5, x2 layers
// R9: GEMM made persistent-per-block: 8 waves x 16 cols (128-col half),
// gg.y=2, T=3 row-tiles per block. breg (B col-slice, K=512) loaded ONCE per
// block; per tile only A staged (64KB LDS, XOR-swizzle, global_load_lds).
// __launch_bounds__(512,4) keeps VGPR<=128 so 2 blocks/CU overlap
// stage-drain with compute. A traffic halved vs R8 (gg.y 4->2).
// Rest unchanged from R8 (counting-sort binA, fp8 agg, parallel scan).
// ---------------------------------------------------------------------------

typedef __attribute__((ext_vector_type(8))) short bf16x8;
typedef __attribute__((ext_vector_type(4))) float f32x4;

__device__ __forceinline__ float bf2f(unsigned short b) {
    union { unsigned u; float f; } x; x.u = ((unsigned)b) << 16; return x.f;
}
__device__ __forceinline__ short f2bf(float f) {
    union { float f; unsigned u; } x; x.f = f;
    unsigned r = x.u + 0x7fffu + ((x.u >> 16) & 1u);
    return (short)(r >> 16);
}
__device__ __forceinline__ unsigned char f2fp8(float f) {
    __hip_fp8_e4m3 q(f);
    return (unsigned char)q.__x;
}
__device__ __forceinline__ float fp82f(unsigned char b) {
    __hip_fp8_e4m3 q; q.__x = (__hip_fp8_storage_t)b;
    return (float)q;
}

// -------------------- CSR construction --------------------

__global__ __launch_bounds__(256) void zero_kernel(int* __restrict__ p, int n4) {
    int i = blockIdx.x * 256 + threadIdx.x;
    if (i < n4) *reinterpret_cast<int4*>(p + i * 4) = (int4){0, 0, 0, 0};
}

__global__ __launch_bounds__(256) void count_kernel(
    const int* __restrict__ ei, int* __restrict__ cnt, int E) {
    int e = blockIdx.x * 256 + threadIdx.x;
    if (e < E) atomicAdd(&cnt[ei[E + e]], 1);
}

// scan1: per-block (1024) local exclusive scan of cnt -> offs, block sums.
__global__ __launch_bounds__(1024) void scan1_kernel(
    const int* __restrict__ cnt, int* __restrict__ offs,
    float* __restrict__ invdeg, int* __restrict__ bsum, int N) {
    __shared__ int wsum[16];
    int lane = threadIdx.x & 63;
    int wid = threadIdx.x >> 6;
    int i = blockIdx.x * 1024 + threadIdx.x;
    int v = (i < N) ? cnt[i] : 0;
    int s = v;
    #pragma unroll
    for (int d = 1; d < 64; d <<= 1) {
        int t = __shfl_up(s, d, 64);
        if (lane >= d) s += t;
    }
    if (lane == 63) wsum[wid] = s;
    __syncthreads();
    if (wid == 0) {
        int w = (lane < 16) ? wsum[lane] : 0;
        int ws = w;
        #pragma unroll
        for (int d = 1; d < 16; d <<= 1) {
            int t = __shfl_up(ws, d, 64);
            if (lane >= d) ws += t;
        }
        if (lane < 16) wsum[lane] = ws - w;          // exclusive wave prefix
    }
    __syncthreads();
    if (i < N) {
        offs[i] = wsum[wid] + s - v;                 // block-local exclusive
        invdeg[i] = 1.0f / (float)(v > 0 ? v : 1);
    }
    if (threadIdx.x == 1023) bsum[blockIdx.x] = wsum[15] + s;
}

__global__ __launch_bounds__(64) void scan2_kernel(
    const int* __restrict__ bsum, int* __restrict__ bpre,
    int* __restrict__ offs, int NB, int N) {
    int lane = threadIdx.x;
    int v = (lane < NB) ? bsum[lane] : 0;
    int s = v;
    #pragma unroll
    for (int d = 1; d < 64; d <<= 1) {
        int t = __shfl_up(s, d, 64);
        if (lane >= d) s += t;
    }
    if (lane < NB) bpre[lane] = s - v;
    if (lane == NB - 1) offs[N] = s;
}

__global__ __launch_bounds__(1024) void scan3_kernel(
    int* __restrict__ offs, const int* __restrict__ bpre, int N) {
    int i = blockIdx.x * 1024 + threadIdx.x;
    if (i < N) offs[i] += bpre[blockIdx.x];
}

// bucket cursors: bucket b covers nodes [b*128, b*128+128); base = offs[b*128]
__global__ __launch_bounds__(256) void initcur_kernel(
    const int* __restrict__ offs, int* __restrict__ bcur, int NBK) {
    int b = blockIdx.x * 256 + threadIdx.x;
    if (b < NBK) bcur[b] = offs[b << 7];
}

// pass A (counting sort per block): chunk = 8192 edges; LDS histogram,
// one global atomic per (block,bucket), LDS cursors hold global positions.
#define BINA_CHUNK 8192
__global__ __launch_bounds__(512) void binA_kernel(
    const int* __restrict__ ei, int* __restrict__ bcur,
    long long* __restrict__ pairs, int E, int NBK) {
    __shared__ int hist[512];
    int base_e = blockIdx.x * BINA_CHUNK;
    int nloc = E - base_e;
    if (nloc > BINA_CHUNK) nloc = BINA_CHUNK;
    for (int b = threadIdx.x; b < NBK; b += 512) hist[b] = 0;
    __syncthreads();
    for (int t = threadIdx.x; t < nloc; t += 512)
        atomicAdd(&hist[ei[E + base_e + t] >> 7], 1);
    __syncthreads();
    for (int b = threadIdx.x; b < NBK; b += 512) {
        int h = hist[b];
        hist[b] = (h > 0) ? atomicAdd(&bcur[b], h) : 0;
    }
    __syncthreads();
    for (int t = threadIdx.x; t < nloc; t += 512) {
        int dst = ei[E + base_e + t];
        int src = ei[base_e + t];
        int pos = atomicAdd(&hist[dst >> 7], 1);
        pairs[pos] = ((long long)dst << 32) | (unsigned)src;
    }
}

// pass B: one block per bucket; LDS cursors; csr writes land in 8KB window.
__global__ __launch_bounds__(256) void binB_kernel(
    const long long* __restrict__ pairs, const int* __restrict__ offs,
    int* __restrict__ csr, int NBK, int N, int E) {
    __shared__ int cur[128];
    int b = blockIdx.x;
    int t = threadIdx.x;
    if (t < 128) {
        int n0 = (b << 7) + t;
        cur[t] = (n0 < N) ? offs[n0] : 0;
    }
    __syncthreads();
    int beg = offs[b << 7];
    int eidx = (b + 1) << 7;
    if (eidx > N) eidx = N;
    int end = offs[eidx];
    for (int i = beg + t; i < end; i += 256) {
        long long p = pairs[i];
        int dst = (int)(p >> 32);
        int src = (int)(p & 0xffffffffLL);
        int pos = atomicAdd(&cur[dst & 127], 1);
        csr[pos] = src;
    }
}

// -------------------- casts / weight prep --------------------

// x f32 -> xb bf16, xq fp8, and copy x into d_out second half.
__global__ __launch_bounds__(256) void cast_x_kernel(
    const float* __restrict__ x, short* __restrict__ xb,
    unsigned char* __restrict__ xq, float* __restrict__ xcopy, int total8) {
    int i = blockIdx.x * 256 + threadIdx.x;
    if (i >= total8) return;
    const float* p = x + (size_t)i * 8;
    float4 v0 = *reinterpret_cast<const float4*>(p);
    float4 v1 = *reinterpret_cast<const float4*>(p + 4);
    bf16x8 t;
    t[0] = f2bf(v0.x); t[1] = f2bf(v0.y); t[2] = f2bf(v0.z); t[3] = f2bf(v0.w);
    t[4] = f2bf(v1.x); t[5] = f2bf(v1.y); t[6] = f2bf(v1.z); t[7] = f2bf(v1.w);
    *reinterpret_cast<bf16x8*>(xb + (size_t)i * 8) = t;
    uchar4 q0, q1;
    q0.x = f2fp8(v0.x); q0.y = f2fp8(v0.y); q0.z = f2fp8(v0.z); q0.w = f2fp8(v0.w);
    q1.x = f2fp8(v1.x); q1.y = f2fp8(v1.y); q1.z = f2fp8(v1.z); q1.w = f2fp8(v1.w);
    *reinterpret_cast<uchar4*>(xq + (size_t)i * 8) = q0;
    *reinterpret_cast<uchar4*>(xq + (size_t)i * 8 + 4) = q1;
    *reinterpret_cast<float4*>(xcopy + (size_t)i * 8) = v0;
    *reinterpret_cast<float4*>(xcopy + (size_t)i * 8 + 4) = v1;
}

// B^T[n][k] = (k<256 ? Wl[k][n] : Wr[k-256][n]), bf16, both layers at once.
__global__ __launch_bounds__(256) void buildB_kernel(
    const float* __restrict__ Wl0, const float* __restrict__ Wr0,
    const float* __restrict__ Wl1, const float* __restrict__ Wr1,
    short* __restrict__ B1T, short* __restrict__ B2T) {
    int idx = blockIdx.x * 256 + threadIdx.x;   // 0 .. 262143
    int sel = idx >> 17;
    int j = idx & 131071;
    int n = j >> 9;
    int k = j & 511;
    const float* Wl = sel ? Wl1 : Wl0;
    const float* Wr = sel ? Wr1 : Wr0;
    float v = (k < 256) ? Wl[k * 256 + n] : Wr[(k - 256) * 256 + n];
    (sel ? B2T : B1T)[j] = f2bf(v);
}

// -------------------- mean aggregation (fp8 gather) --------------------
// One wave per node; lane t owns elements [4t,4t+4). 8 rows in flight.
__global__ __launch_bounds__(256) void agg_kernel(
    const unsigned char* __restrict__ feat,
    const int* __restrict__ offs, const int* __restrict__ csr,
    const float* __restrict__ invdeg,
    short* __restrict__ outp, int N) {
    int wave = threadIdx.x >> 6;
    int lane = threadIdx.x & 63;
    int node = blockIdx.x * 4 + wave;
    if (node >= N) return;
    int beg = offs[node];
    int end = offs[node + 1];
    int c = lane * 4;

    float a[4][4];
    #pragma unroll
    for (int u = 0; u < 4; ++u)
        #pragma unroll
        for (int k = 0; k < 4; ++k) a[u][k] = 0.f;

    int deg = end - beg;
    int n8 = deg & ~7;
    for (int t = 0; t < n8; t += 8) {
        int s0 = csr[beg + t];     int s1 = csr[beg + t + 1];
        int s2 = csr[beg + t + 2]; int s3 = csr[beg + t + 3];
        int s4 = csr[beg + t + 4]; int s5 = csr[beg + t + 5];
        int s6 = csr[beg + t + 6]; int s7 = csr[beg + t + 7];
        unsigned u0 = *reinterpret_cast<const unsigned*>(feat + (size_t)s0 * 256 + c);
        unsigned u1 = *reinterpret_cast<const unsigned*>(feat + (size_t)s1 * 256 + c);
        unsigned u2 = *reinterpret_cast<const unsigned*>(feat + (size_t)s2 * 256 + c);
        unsigned u3 = *reinterpret_cast<const unsigned*>(feat + (size_t)s3 * 256 + c);
        unsigned u4 = *reinterpret_cast<const unsigned*>(feat + (size_t)s4 * 256 + c);
        unsigned u5 = *reinterpret_cast<const unsigned*>(feat + (size_t)s5 * 256 + c);
        unsigned u6 = *reinterpret_cast<const unsigned*>(feat + (size_t)s6 * 256 + c);
        unsigned u7 = *reinterpret_cast<const unsigned*>(feat + (size_t)s7 * 256 + c);
        #pragma unroll
        for (int k = 0; k < 4; ++k) a[0][k] += fp82f((u0 >> (8 * k)) & 0xff);
        #pragma unroll
        for (int k = 0; k < 4; ++k) a[1][k] += fp82f((u1 >> (8 * k)) & 0xff);
        #pragma unroll
        for (int k = 0; k < 4; ++k) a[2][k] += fp82f((u2 >> (8 * k)) & 0xff);
        #pragma unroll
        for (int k = 0; k < 4; ++k) a[3][k] += fp82f((u3 >> (8 * k)) & 0xff);
        #pragma unroll
        for (int k = 0; k < 4; ++k) a[0][k] += fp82f((u4 >> (8 * k)) & 0xff);
        #pragma unroll
        for (int k = 0; k < 4; ++k) a[1][k] += fp82f((u5 >> (8 * k)) & 0xff);
        #pragma unroll
        for (int k = 0; k < 4; ++k) a[2][k] += fp82f((u6 >> (8 * k)) & 0xff);
        #pragma unroll
        for (int k = 0; k < 4; ++k) a[3][k] += fp82f((u7 >> (8 * k)) & 0xff);
    }
    for (int e = beg + n8; e < end; ++e) {
        int s = csr[e];
        unsigned u = *reinterpret_cast<const unsigned*>(feat + (size_t)s * 256 + c);
        #pragma unroll
        for (int k = 0; k < 4; ++k) a[0][k] += fp82f((u >> (8 * k)) & 0xff);
    }
    float inv = invdeg[node];
    short4 o;
    o.x = f2bf((a[0][0] + a[1][0] + a[2][0] + a[3][0]) * inv);
    o.y = f2bf((a[0][1] + a[1][1] + a[2][1] + a[3][1]) * inv);
    o.z = f2bf((a[0][2] + a[1][2] + a[2][2] + a[3][2]) * inv);
    o.w = f2bf((a[0][3] + a[1][3] + a[2][3] + a[3][3]) * inv);
    *reinterpret_cast<short4*>(&outp[(size_t)node * 256 + c]) = o;
}

// -------------------- fused GEMM + bias + leaky --------------------
// C[M][256] = leaky( [AL | AR][M][512](bf16) @ B[512][256] + bias )
// Grid: (ceil(tiles/T), 2). Block: 512 threads = 8 waves; wave w owns 16
// cols c0 = blockIdx.y*128 + w*16. breg[16] (wave's B col-slice, K=512)
// loaded ONCE per block. Per row-tile (64 rows): stage A-tile 64KB LDS
// (global_load_lds 16B, XOR-swizzle (r&15), pre-swizzled global src),
// sync, 16 k-steps of 4 ds_read_b128 + 4 MFMA, write, sync.
// 2 blocks/CU resident (64KB LDS, VGPR<=128) -> stage/compute overlap
// across blocks. C/D: lane l, reg r -> row (l>>4)*4+r, col l&15.
#define GEMM_T 3
template <int OUT_MODE>   // 0: bf16 + fp8 out, 1: f32 out
__global__ __launch_bounds__(512, 4) void gemm_kernel(
    const short* __restrict__ AL, const short* __restrict__ AR,
    const short* __restrict__ BT, const float* __restrict__ bias,
    void* __restrict__ Cout, unsigned char* __restrict__ Cq, int M) {
    __shared__ short ldsA[64 * 512];
    int wave = threadIdx.x >> 6;        // 0..7
    int lane = threadIdx.x & 63;
    int l16 = lane & 15;
    int lhi = lane >> 4;
    int c0 = blockIdx.y * 128 + wave * 16;
    int t0 = blockIdx.x * GEMM_T;

    // ---- B column-slice into registers, once per block ----
    bf16x8 breg[16];
    #pragma unroll
    for (int kk = 0; kk < 16; ++kk)
        breg[kk] = *reinterpret_cast<const bf16x8*>(
            &BT[(size_t)(c0 + l16) * 512 + kk * 32 + lhi * 8]);
    float bc = bias[c0 + l16];

    for (int t = 0; t < GEMM_T; ++t) {
        int row0 = (t0 + t) * 64;
        if (row0 >= M) break;

        // ---- stage A tile: wave w stages rows i*8+w ----
        #pragma unroll
        for (int i = 0; i < 8; ++i) {
            int r = i * 8 + wave;
            int grow = row0 + r;
            if (grow >= M) grow = M - 1;
            int csw = (lane * 8) ^ ((r & 15) << 3);   // swizzled short offset
            const short* src = (csw < 256)
                ? AL + (size_t)grow * 256 + csw
                : AR + (size_t)grow * 256 + (csw - 256);
            __builtin_amdgcn_global_load_lds(
                (const __attribute__((address_space(1))) unsigned int*)src,
                (__attribute__((address_space(3))) unsigned int*)&ldsA[r * 512],
                16, 0, 0);
        }
        __syncthreads();

        f32x4 acc[4];
        #pragma unroll
        for (int mt = 0; mt < 4; ++mt) acc[mt] = (f32x4){0.f, 0.f, 0.f, 0.f};

        #pragma unroll
        for (int kk = 0; kk < 16; ++kk) {
            bf16x8 a[4];
            #pragma unroll
            for (int mt = 0; mt < 4; ++mt) {
                int r = mt * 16 + l16;
                int ks = (kk * 32 + lhi * 8) ^ ((r & 15) << 3);
                a[mt] = *reinterpret_cast<const bf16x8*>(&ldsA[r * 512 + ks]);
            }
            #pragma unroll
            for (int mt = 0; mt < 4; ++mt)
                acc[mt] = __builtin_amdgcn_mfma_f32_16x16x32_bf16(
                    a[mt], breg[kk], acc[mt], 0, 0, 0);
        }

        #pragma unroll
        for (int mt = 0; mt < 4; ++mt) {
            #pragma unroll
            for (int r = 0; r < 4; ++r) {
                int grow = row0 + mt * 16 + lhi * 4 + r;
                if (grow >= M) continue;
                int gcol = c0 + l16;
                float v = acc[mt][r] + bc;
                v = (v >= 0.f) ? v : 0.5f * v;
                if (OUT_MODE == 0) {
                    ((short*)Cout)[(size_t)grow * 256 + gcol] = f2bf(v);
                    Cq[(size_t)grow * 256 + gcol] = f2fp8(v);
                } else {
                    ((float*)Cout)[(size_t)grow * 256 + gcol] = v;
                }
            }
        }
        __syncthreads();    // all waves done reading ldsA before next stage
    }
}

// -------------------- launch --------------------

extern "C" void kernel_launch(void* const* d_in, const int* in_sizes, int n_in,
                              void* d_out, int out_size, void* d_ws, size_t ws_size,
                              hipStream_t stream) {
    const float* x   = (const float*)d_in[0];
    const int*   ei  = (const int*)d_in[1];   // int64 in ref -> int32 from harness
    const float* Wl0 = (const float*)d_in[2];
    const float* bl0 = (const float*)d_in[3];
    const float* Wr0 = (const float*)d_in[4];
    const float* Wl1 = (const float*)d_in[5];
    const float* bl1 = (const float*)d_in[6];
    const float* Wr1 = (const float*)d_in[7];

    const int N = in_sizes[0] / 256;
    const int E = in_sizes[1] / 2;
    const int NBK = (N + 127) / 128;           // <= 512

    char* ws = (char*)d_ws;
    size_t o = 0;
    auto alloc = [&](size_t bytes) {
        size_t p = o;
        o = (o + bytes + 255) & ~(size_t)255;
        return p;
    };
    int*   cnt    = (int*)  (ws + alloc((size_t)N * 4));
    int*   offs   = (int*)  (ws + alloc((size_t)(N + 1) * 4));
    float* invdeg = (float*)(ws + alloc((size_t)N * 4));
    int*   bsum   = (int*)  (ws + alloc(64 * 4));
    int*   bpre   = (int*)  (ws + alloc(64 * 4));
    int*   bcur   = (int*)  (ws + alloc((size_t)NBK * 4));
    long long* pairs = (long long*)(ws + alloc((size_t)E * 8));
    int*   csr    = (int*)  (ws + alloc((size_t)E * 4));
    short* xb     = (short*)(ws + alloc((size_t)N * 256 * 2));
    short* meanb  = (short*)(ws + alloc((size_t)N * 256 * 2));   // reused L0/L1
    short* h0     = (short*)(ws + alloc((size_t)N * 256 * 2));
    unsigned char* xq  = (unsigned char*)(ws + alloc((size_t)N * 256));
    unsigned char* h0q = (unsigned char*)(ws + alloc((size_t)N * 256));
    short* B1T    = (short*)(ws + alloc(262144));
    short* B2T    = (short*)(ws + alloc(262144));

    int eb = (E + 255) / 256;
    int NB = (N + 1023) / 1024;
    zero_kernel<<<((N + 3) / 4 + 255) / 256, 256, 0, stream>>>(cnt, (N + 3) / 4);
    count_kernel<<<eb, 256, 0, stream>>>(ei, cnt, E);
    scan1_kernel<<<NB, 1024, 0, stream>>>(cnt, offs, invdeg, bsum, N);
    scan2_kernel<<<1, 64, 0, stream>>>(bsum, bpre, offs, NB, N);
    scan3_kernel<<<NB, 1024, 0, stream>>>(offs, bpre, N);
    initcur_kernel<<<(NBK + 255) / 256, 256, 0, stream>>>(offs, bcur, NBK);
    binA_kernel<<<(E + BINA_CHUNK - 1) / BINA_CHUNK, 512, 0, stream>>>(
        ei, bcur, pairs, E, NBK);
    binB_kernel<<<NBK, 256, 0, stream>>>(pairs, offs, csr, NBK, N, E);

    cast_x_kernel<<<(N * 32 + 255) / 256, 256, 0, stream>>>(
        x, xb, xq, (float*)d_out + (size_t)N * 256, N * 32);
    buildB_kernel<<<1024, 256, 0, stream>>>(Wl0, Wr0, Wl1, Wr1, B1T, B2T);

    int ab = (N + 3) / 4;
    int tiles = (N + 63) / 64;
    dim3 gg((tiles + GEMM_T - 1) / GEMM_T, 2);
    // layer 0
    agg_kernel<<<ab, 256, 0, stream>>>(xq, offs, csr, invdeg, meanb, N);
    gemm_kernel<0><<<gg, 512, 0, stream>>>(meanb, xb, B1T, bl0, h0, h0q, N);
    // layer 1
    agg_kernel<<<ab, 256, 0, stream>>>(h0q, offs, csr, invdeg, meanb, N);
    gemm_kernel<1><<<gg, 512, 0, stream>>>(meanb, h0, B2T, bl1, d_out, nullptr, N);
}

// Round 10
// 259.841 us; speedup vs baseline: 1.3110x; 1.2117x over previous
//
#include <hip/hip_runtime.h>
#include <hip/hip_fp8.h>

// ---------------------------------------------------------------------------
// GraphSAGE 2-layer encoder, MI355X.
//   out = leaky( mean_{j->i}(h_j) @ Wl + b + h_i @ Wr ), slope 0.5, x2 layers
// R10: GEMM = persistent 16-wave block (all 256 cols -> A fetched once),
// 32-row tiles, LDS double-buffer with counted s_waitcnt vmcnt(2) + raw
// s_barrier (T3/T4 minimum recipe): prefetch of tile t+1 stays in flight
// across the barrier while tile t computes. breg (B col-slice) register-
// resident per wave. Rest unchanged from R9.
// ---------------------------------------------------------------------------

typedef __attribute__((ext_vector_type(8))) short bf16x8;
typedef __attribute__((ext_vector_type(4))) float f32x4;

__device__ __forceinline__ float bf2f(unsigned short b) {
    union { unsigned u; float f; } x; x.u = ((unsigned)b) << 16; return x.f;
}
__device__ __forceinline__ short f2bf(float f) {
    union { float f; unsigned u; } x; x.f = f;
    unsigned r = x.u + 0x7fffu + ((x.u >> 16) & 1u);
    return (short)(r >> 16);
}
__device__ __forceinline__ unsigned char f2fp8(float f) {
    __hip_fp8_e4m3 q(f);
    return (unsigned char)q.__x;
}
__device__ __forceinline__ float fp82f(unsigned char b) {
    __hip_fp8_e4m3 q; q.__x = (__hip_fp8_storage_t)b;
    return (float)q;
}

// -------------------- CSR construction --------------------

__global__ __launch_bounds__(256) void zero_kernel(int* __restrict__ p, int n4) {
    int i = blockIdx.x * 256 + threadIdx.x;
    if (i < n4) *reinterpret_cast<int4*>(p + i * 4) = (int4){0, 0, 0, 0};
}

__global__ __launch_bounds__(256) void count_kernel(
    const int* __restrict__ ei, int* __restrict__ cnt, int E) {
    int e = blockIdx.x * 256 + threadIdx.x;
    if (e < E) atomicAdd(&cnt[ei[E + e]], 1);
}

// scan1: per-block (1024) local exclusive scan of cnt -> offs, block sums.
__global__ __launch_bounds__(1024) void scan1_kernel(
    const int* __restrict__ cnt, int* __restrict__ offs,
    float* __restrict__ invdeg, int* __restrict__ bsum, int N) {
    __shared__ int wsum[16];
    int lane = threadIdx.x & 63;
    int wid = threadIdx.x >> 6;
    int i = blockIdx.x * 1024 + threadIdx.x;
    int v = (i < N) ? cnt[i] : 0;
    int s = v;
    #pragma unroll
    for (int d = 1; d < 64; d <<= 1) {
        int t = __shfl_up(s, d, 64);
        if (lane >= d) s += t;
    }
    if (lane == 63) wsum[wid] = s;
    __syncthreads();
    if (wid == 0) {
        int w = (lane < 16) ? wsum[lane] : 0;
        int ws = w;
        #pragma unroll
        for (int d = 1; d < 16; d <<= 1) {
            int t = __shfl_up(ws, d, 64);
            if (lane >= d) ws += t;
        }
        if (lane < 16) wsum[lane] = ws - w;          // exclusive wave prefix
    }
    __syncthreads();
    if (i < N) {
        offs[i] = wsum[wid] + s - v;                 // block-local exclusive
        invdeg[i] = 1.0f / (float)(v > 0 ? v : 1);
    }
    if (threadIdx.x == 1023) bsum[blockIdx.x] = wsum[15] + s;
}

__global__ __launch_bounds__(64) void scan2_kernel(
    const int* __restrict__ bsum, int* __restrict__ bpre,
    int* __restrict__ offs, int NB, int N) {
    int lane = threadIdx.x;
    int v = (lane < NB) ? bsum[lane] : 0;
    int s = v;
    #pragma unroll
    for (int d = 1; d < 64; d <<= 1) {
        int t = __shfl_up(s, d, 64);
        if (lane >= d) s += t;
    }
    if (lane < NB) bpre[lane] = s - v;
    if (lane == NB - 1) offs[N] = s;
}

__global__ __launch_bounds__(1024) void scan3_kernel(
    int* __restrict__ offs, const int* __restrict__ bpre, int N) {
    int i = blockIdx.x * 1024 + threadIdx.x;
    if (i < N) offs[i] += bpre[blockIdx.x];
}

// bucket cursors: bucket b covers nodes [b*128, b*128+128); base = offs[b*128]
__global__ __launch_bounds__(256) void initcur_kernel(
    const int* __restrict__ offs, int* __restrict__ bcur, int NBK) {
    int b = blockIdx.x * 256 + threadIdx.x;
    if (b < NBK) bcur[b] = offs[b << 7];
}

// pass A (counting sort per block): chunk = 8192 edges; LDS histogram,
// one global atomic per (block,bucket), LDS cursors hold global positions.
#define BINA_CHUNK 8192
__global__ __launch_bounds__(512) void binA_kernel(
    const int* __restrict__ ei, int* __restrict__ bcur,
    long long* __restrict__ pairs, int E, int NBK) {
    __shared__ int hist[512];
    int base_e = blockIdx.x * BINA_CHUNK;
    int nloc = E - base_e;
    if (nloc > BINA_CHUNK) nloc = BINA_CHUNK;
    for (int b = threadIdx.x; b < NBK; b += 512) hist[b] = 0;
    __syncthreads();
    for (int t = threadIdx.x; t < nloc; t += 512)
        atomicAdd(&hist[ei[E + base_e + t] >> 7], 1);
    __syncthreads();
    for (int b = threadIdx.x; b < NBK; b += 512) {
        int h = hist[b];
        hist[b] = (h > 0) ? atomicAdd(&bcur[b], h) : 0;
    }
    __syncthreads();
    for (int t = threadIdx.x; t < nloc; t += 512) {
        int dst = ei[E + base_e + t];
        int src = ei[base_e + t];
        int pos = atomicAdd(&hist[dst >> 7], 1);
        pairs[pos] = ((long long)dst << 32) | (unsigned)src;
    }
}

// pass B: one block per bucket; LDS cursors; csr writes land in 8KB window.
__global__ __launch_bounds__(256) void binB_kernel(
    const long long* __restrict__ pairs, const int* __restrict__ offs,
    int* __restrict__ csr, int NBK, int N, int E) {
    __shared__ int cur[128];
    int b = blockIdx.x;
    int t = threadIdx.x;
    if (t < 128) {
        int n0 = (b << 7) + t;
        cur[t] = (n0 < N) ? offs[n0] : 0;
    }
    __syncthreads();
    int beg = offs[b << 7];
    int eidx = (b + 1) << 7;
    if (eidx > N) eidx = N;
    int end = offs[eidx];
    for (int i = beg + t; i < end; i += 256) {
        long long p = pairs[i];
        int dst = (int)(p >> 32);
        int src = (int)(p & 0xffffffffLL);
        int pos = atomicAdd(&cur[dst & 127], 1);
        csr[pos] = src;
    }
}

// -------------------- casts / weight prep --------------------

// x f32 -> xb bf16, xq fp8, and copy x into d_out second half.
__global__ __launch_bounds__(256) void cast_x_kernel(
    const float* __restrict__ x, short* __restrict__ xb,
    unsigned char* __restrict__ xq, float* __restrict__ xcopy, int total8) {
    int i = blockIdx.x * 256 + threadIdx.x;
    if (i >= total8) return;
    const float* p = x + (size_t)i * 8;
    float4 v0 = *reinterpret_cast<const float4*>(p);
    float4 v1 = *reinterpret_cast<const float4*>(p + 4);
    bf16x8 t;
    t[0] = f2bf(v0.x); t[1] = f2bf(v0.y); t[2] = f2bf(v0.z); t[3] = f2bf(v0.w);
    t[4] = f2bf(v1.x); t[5] = f2bf(v1.y); t[6] = f2bf(v1.z); t[7] = f2bf(v1.w);
    *reinterpret_cast<bf16x8*>(xb + (size_t)i * 8) = t;
    uchar4 q0, q1;
    q0.x = f2fp8(v0.x); q0.y = f2fp8(v0.y); q0.z = f2fp8(v0.z); q0.w = f2fp8(v0.w);
    q1.x = f2fp8(v1.x); q1.y = f2fp8(v1.y); q1.z = f2fp8(v1.z); q1.w = f2fp8(v1.w);
    *reinterpret_cast<uchar4*>(xq + (size_t)i * 8) = q0;
    *reinterpret_cast<uchar4*>(xq + (size_t)i * 8 + 4) = q1;
    *reinterpret_cast<float4*>(xcopy + (size_t)i * 8) = v0;
    *reinterpret_cast<float4*>(xcopy + (size_t)i * 8 + 4) = v1;
}

// B^T[n][k] = (k<256 ? Wl[k][n] : Wr[k-256][n]), bf16, both layers at once.
__global__ __launch_bounds__(256) void buildB_kernel(
    const float* __restrict__ Wl0, const float* __restrict__ Wr0,
    const float* __restrict__ Wl1, const float* __restrict__ Wr1,
    short* __restrict__ B1T, short* __restrict__ B2T) {
    int idx = blockIdx.x * 256 + threadIdx.x;   // 0 .. 262143
    int sel = idx >> 17;
    int j = idx & 131071;
    int n = j >> 9;
    int k = j & 511;
    const float* Wl = sel ? Wl1 : Wl0;
    const float* Wr = sel ? Wr1 : Wr0;
    float v = (k < 256) ? Wl[k * 256 + n] : Wr[(k - 256) * 256 + n];
    (sel ? B2T : B1T)[j] = f2bf(v);
}

// -------------------- mean aggregation (fp8 gather) --------------------
// One wave per node; lane t owns elements [4t,4t+4). 8 rows in flight.
__global__ __launch_bounds__(256) void agg_kernel(
    const unsigned char* __restrict__ feat,
    const int* __restrict__ offs, const int* __restrict__ csr,
    const float* __restrict__ invdeg,
    short* __restrict__ outp, int N) {
    int wave = threadIdx.x >> 6;
    int lane = threadIdx.x & 63;
    int node = blockIdx.x * 4 + wave;
    if (node >= N) return;
    int beg = offs[node];
    int end = offs[node + 1];
    int c = lane * 4;

    float a[4][4];
    #pragma unroll
    for (int u = 0; u < 4; ++u)
        #pragma unroll
        for (int k = 0; k < 4; ++k) a[u][k] = 0.f;

    int deg = end - beg;
    int n8 = deg & ~7;
    for (int t = 0; t < n8; t += 8) {
        int s0 = csr[beg + t];     int s1 = csr[beg + t + 1];
        int s2 = csr[beg + t + 2]; int s3 = csr[beg + t + 3];
        int s4 = csr[beg + t + 4]; int s5 = csr[beg + t + 5];
        int s6 = csr[beg + t + 6]; int s7 = csr[beg + t + 7];
        unsigned u0 = *reinterpret_cast<const unsigned*>(feat + (size_t)s0 * 256 + c);
        unsigned u1 = *reinterpret_cast<const unsigned*>(feat + (size_t)s1 * 256 + c);
        unsigned u2 = *reinterpret_cast<const unsigned*>(feat + (size_t)s2 * 256 + c);
        unsigned u3 = *reinterpret_cast<const unsigned*>(feat + (size_t)s3 * 256 + c);
        unsigned u4 = *reinterpret_cast<const unsigned*>(feat + (size_t)s4 * 256 + c);
        unsigned u5 = *reinterpret_cast<const unsigned*>(feat + (size_t)s5 * 256 + c);
        unsigned u6 = *reinterpret_cast<const unsigned*>(feat + (size_t)s6 * 256 + c);
        unsigned u7 = *reinterpret_cast<const unsigned*>(feat + (size_t)s7 * 256 + c);
        #pragma unroll
        for (int k = 0; k < 4; ++k) a[0][k] += fp82f((u0 >> (8 * k)) & 0xff);
        #pragma unroll
        for (int k = 0; k < 4; ++k) a[1][k] += fp82f((u1 >> (8 * k)) & 0xff);
        #pragma unroll
        for (int k = 0; k < 4; ++k) a[2][k] += fp82f((u2 >> (8 * k)) & 0xff);
        #pragma unroll
        for (int k = 0; k < 4; ++k) a[3][k] += fp82f((u3 >> (8 * k)) & 0xff);
        #pragma unroll
        for (int k = 0; k < 4; ++k) a[0][k] += fp82f((u4 >> (8 * k)) & 0xff);
        #pragma unroll
        for (int k = 0; k < 4; ++k) a[1][k] += fp82f((u5 >> (8 * k)) & 0xff);
        #pragma unroll
        for (int k = 0; k < 4; ++k) a[2][k] += fp82f((u6 >> (8 * k)) & 0xff);
        #pragma unroll
        for (int k = 0; k < 4; ++k) a[3][k] += fp82f((u7 >> (8 * k)) & 0xff);
    }
    for (int e = beg + n8; e < end; ++e) {
        int s = csr[e];
        unsigned u = *reinterpret_cast<const unsigned*>(feat + (size_t)s * 256 + c);
        #pragma unroll
        for (int k = 0; k < 4; ++k) a[0][k] += fp82f((u >> (8 * k)) & 0xff);
    }
    float inv = invdeg[node];
    short4 o;
    o.x = f2bf((a[0][0] + a[1][0] + a[2][0] + a[3][0]) * inv);
    o.y = f2bf((a[0][1] + a[1][1] + a[2][1] + a[3][1]) * inv);
    o.z = f2bf((a[0][2] + a[1][2] + a[2][2] + a[3][2]) * inv);
    o.w = f2bf((a[0][3] + a[1][3] + a[2][3] + a[3][3]) * inv);
    *reinterpret_cast<short4*>(&outp[(size_t)node * 256 + c]) = o;
}

// -------------------- fused GEMM + bias + leaky --------------------
// C[M][256] = leaky( [AL | AR][M][512](bf16) @ B[512][256] + bias )
// Persistent grid of 256 blocks, 1024 thr = 16 waves; wave w owns cols
// [w*16, w*16+16) -- all 256 cols per block, so A is fetched ONCE total.
// breg[16] = wave's B col-slice (K=512), loaded once per block.
// Tiles of 32 rows, LDS double-buffer 2x32KB. Pipeline per tile:
//   STAGE(next, buf^1) ; s_waitcnt vmcnt(2) (current buf's 2 loads done,
//   prefetch stays in flight) ; raw s_barrier ; sched_barrier ;
//   compute (16 k-steps x {2 ds_read_b128 + 2 MFMA}) ; stores ; raw barrier.
// XOR-swizzle (r&15) via pre-swizzled GLOBAL source, linear LDS dest.
// C/D: lane l, reg r -> row (l>>4)*4+r, col l&15.
template <int OUT_MODE>   // 0: bf16 + fp8 out, 1: f32 out
__global__ __launch_bounds__(1024, 4) void gemm_kernel(
    const short* __restrict__ AL, const short* __restrict__ AR,
    const short* __restrict__ BT, const float* __restrict__ bias,
    void* __restrict__ Cout, unsigned char* __restrict__ Cq,
    int M, int ntiles) {
    __shared__ short ldsA[2][32 * 512];
    int wave = threadIdx.x >> 6;        // 0..15
    int lane = threadIdx.x & 63;
    int l16 = lane & 15;
    int lhi = lane >> 4;
    int c0 = wave * 16;

    // ---- B column-slice into registers, once per block ----
    bf16x8 breg[16];
    #pragma unroll
    for (int kk = 0; kk < 16; ++kk)
        breg[kk] = *reinterpret_cast<const bf16x8*>(
            &BT[(size_t)(c0 + l16) * 512 + kk * 32 + lhi * 8]);
    float bc = bias[c0 + l16];

    // stage tile tt into buffer buf: wave w stages rows {w, 16+w}
    auto STAGE = [&](int tt, int buf) {
        #pragma unroll
        for (int i = 0; i < 2; ++i) {
            int r = i * 16 + wave;
            int grow = tt * 32 + r;
            if (grow >= M) grow = M - 1;
            int csw = (lane * 8) ^ ((r & 15) << 3);   // swizzled short offset
            const short* src = (csw < 256)
                ? AL + (size_t)grow * 256 + csw
                : AR + (size_t)grow * 256 + (csw - 256);
            __builtin_amdgcn_global_load_lds(
                (const __attribute__((address_space(1))) unsigned int*)src,
                (__attribute__((address_space(3))) unsigned int*)
                    &ldsA[buf][r * 512],
                16, 0, 0);
        }
    };

    int t = blockIdx.x;
    int stride = gridDim.x;
    if (t >= ntiles) return;
    STAGE(t, 0);
    int buf = 0;
    for (; t < ntiles; t += stride) {
        int tn = t + stride;
        bool havenext = (tn < ntiles);
        if (havenext) STAGE(tn, buf ^ 1);

        if (havenext) {
            asm volatile("s_waitcnt vmcnt(2)" ::: "memory");
        } else {
            asm volatile("s_waitcnt vmcnt(0)" ::: "memory");
        }
        __builtin_amdgcn_s_barrier();
        __builtin_amdgcn_sched_barrier(0);

        int row0 = t * 32;
        f32x4 acc[2];
        acc[0] = (f32x4){0.f, 0.f, 0.f, 0.f};
        acc[1] = (f32x4){0.f, 0.f, 0.f, 0.f};

        const short* lb = &ldsA[buf][0];
        #pragma unroll
        for (int kk = 0; kk < 16; ++kk) {
            bf16x8 a0, a1;
            {
                int r = l16;
                int ks = (kk * 32 + lhi * 8) ^ ((r & 15) << 3);
                a0 = *reinterpret_cast<const bf16x8*>(&lb[r * 512 + ks]);
            }
            {
                int r = 16 + l16;
                int ks = (kk * 32 + lhi * 8) ^ ((r & 15) << 3);
                a1 = *reinterpret_cast<const bf16x8*>(&lb[r * 512 + ks]);
            }
            acc[0] = __builtin_amdgcn_mfma_f32_16x16x32_bf16(
                a0, breg[kk], acc[0], 0, 0, 0);
            acc[1] = __builtin_amdgcn_mfma_f32_16x16x32_bf16(
                a1, breg[kk], acc[1], 0, 0, 0);
        }

        #pragma unroll
        for (int mt = 0; mt < 2; ++mt) {
            #pragma unroll
            for (int r = 0; r < 4; ++r) {
                int grow = row0 + mt * 16 + lhi * 4 + r;
                if (grow >= M) continue;
                int gcol = c0 + l16;
                float v = acc[mt][r] + bc;
                v = (v >= 0.f) ? v : 0.5f * v;
                if (OUT_MODE == 0) {
                    ((short*)Cout)[(size_t)grow * 256 + gcol] = f2bf(v);
                    Cq[(size_t)grow * 256 + gcol] = f2fp8(v);
                } else {
                    ((float*)Cout)[(size_t)grow * 256 + gcol] = v;
                }
            }
        }
        __builtin_amdgcn_s_barrier();   // all waves done reading ldsA[buf]
        buf ^= 1;
    }
}

// -------------------- launch --------------------

extern "C" void kernel_launch(void* const* d_in, const int* in_sizes, int n_in,
                              void* d_out, int out_size, void* d_ws, size_t ws_size,
                              hipStream_t stream) {
    const float* x   = (const float*)d_in[0];
    const int*   ei  = (const int*)d_in[1];   // int64 in ref -> int32 from harness
    const float* Wl0 = (const float*)d_in[2];
    const float* bl0 = (const float*)d_in[3];
    const float* Wr0 = (const float*)d_in[4];
    const float* Wl1 = (const float*)d_in[5];
    const float* bl1 = (const float*)d_in[6];
    const float* Wr1 = (const float*)d_in[7];

    const int N = in_sizes[0] / 256;
    const int E = in_sizes[1] / 2;
    const int NBK = (N + 127) / 128;           // <= 512

    char* ws = (char*)d_ws;
    size_t o = 0;
    auto alloc = [&](size_t bytes) {
        size_t p = o;
        o = (o + bytes + 255) & ~(size_t)255;
        return p;
    };
    int*   cnt    = (int*)  (ws + alloc((size_t)N * 4));
    int*   offs   = (int*)  (ws + alloc((size_t)(N + 1) * 4));
    float* invdeg = (float*)(ws + alloc((size_t)N * 4));
    int*   bsum   = (int*)  (ws + alloc(64 * 4));
    int*   bpre   = (int*)  (ws + alloc(64 * 4));
    int*   bcur   = (int*)  (ws + alloc((size_t)NBK * 4));
    long long* pairs = (long long*)(ws + alloc((size_t)E * 8));
    int*   csr    = (int*)  (ws + alloc((size_t)E * 4));
    short* xb     = (short*)(ws + alloc((size_t)N * 256 * 2));
    short* meanb  = (short*)(ws + alloc((size_t)N * 256 * 2));   // reused L0/L1
    short* h0     = (short*)(ws + alloc((size_t)N * 256 * 2));
    unsigned char* xq  = (unsigned char*)(ws + alloc((size_t)N * 256));
    unsigned char* h0q = (unsigned char*)(ws + alloc((size_t)N * 256));
    short* B1T    = (short*)(ws + alloc(262144));
    short* B2T    = (short*)(ws + alloc(262144));

    int eb = (E + 255) / 256;
    int NB = (N + 1023) / 1024;
    zero_kernel<<<((N + 3) / 4 + 255) / 256, 256, 0, stream>>>(cnt, (N + 3) / 4);
    count_kernel<<<eb, 256, 0, stream>>>(ei, cnt, E);
    scan1_kernel<<<NB, 1024, 0, stream>>>(cnt, offs, invdeg, bsum, N);
    scan2_kernel<<<1, 64, 0, stream>>>(bsum, bpre, offs, NB, N);
    scan3_kernel<<<NB, 1024, 0, stream>>>(offs, bpre, N);
    initcur_kernel<<<(NBK + 255) / 256, 256, 0, stream>>>(offs, bcur, NBK);
    binA_kernel<<<(E + BINA_CHUNK - 1) / BINA_CHUNK, 512, 0, stream>>>(
        ei, bcur, pairs, E, NBK);
    binB_kernel<<<NBK, 256, 0, stream>>>(pairs, offs, csr, NBK, N, E);

    cast_x_kernel<<<(N * 32 + 255) / 256, 256, 0, stream>>>(
        x, xb, xq, (float*)d_out + (size_t)N * 256, N * 32);
    buildB_kernel<<<1024, 256, 0, stream>>>(Wl0, Wr0, Wl1, Wr1, B1T, B2T);

    int ab = (N + 3) / 4;
    int ntiles = (N + 31) / 32;
    int gblocks = 256;
    // layer 0
    agg_kernel<<<ab, 256, 0, stream>>>(xq, offs, csr, invdeg, meanb, N);
    gemm_kernel<0><<<gblocks, 1024, 0, stream>>>(
        meanb, xb, B1T, bl0, h0, h0q, N, ntiles);
    // layer 1
    agg_kernel<<<ab, 256, 0, stream>>>(h0q, offs, csr, invdeg, meanb, N);
    gemm_kernel<1><<<gblocks, 1024, 0, stream>>>(
        meanb, h0, B2T, bl1, d_out, nullptr, N, ntiles);
}